// Round 3
// baseline (715.492 us; speedup 1.0000x reference)
//
#include <hip/hip_runtime.h>

// Problem: B=4096, S=256, F=64, K=16, L=256
//   logits[b,k,f] = sum_s x[b,s,f] * W[f,s,k]   (x NaN->0)
//   idx[b,f] = argmax_k logits[b,k,f]           (first max wins)
//   out[b,f,l] = snippet_list[f, idx[b,f], l]
constexpr int Bn = 4096, Sn = 256, Fn = 64, Kn = 16;

// W[f][s][k] -> Wt[s][f][k]  (1 MB, coalesced)
__global__ void transpose_w_kernel(const float* __restrict__ W, float* __restrict__ Wt) {
  int t = blockIdx.x * 256 + threadIdx.x;     // t == (s*64+f)*16+k
  int k = t & 15, f = (t >> 4) & 63, s = t >> 10;
  Wt[t] = W[(f * Sn + s) * Kn + k];
}

// Block = 256 threads (4 waves), covers 4 batches; wave w owns s-quarter
// [w*64, w*64+64) processed as 16 chunks of 4 s.
// lane = f. acc[4 b][16 k] per thread.
// x is staged through wave-private double-buffered LDS (4 KB/chunk/wave),
// loaded 2 chunks ahead as coalesced float4 -> prefetch depth no longer
// limited by accumulator register pressure.
template <bool TR>
__global__ __launch_bounds__(256, 4) void fused_kernel(
    const float* __restrict__ x, const float* __restrict__ Wsrc,
    const float4* __restrict__ snip4, float4* __restrict__ out4) {
  // main phase: x staging [2 buf][4 wave][4 b][4 s][64 f] = 32 KB
  // reduce phase (after barrier): aliased as red[2][4][16][64] = 32 KB
  __shared__ __align__(16) char smem[32 * 1024];
  __shared__ int idxs[4][64];
  float* stage = (float*)smem;
  float (*red)[4][16][64] = (float(*)[4][16][64])smem;

  const int tid = threadIdx.x;
  const int lane = tid & 63;           // f
  const int w = tid >> 6;              // s-quarter
  const int b0 = blockIdx.x * 4;
  const int sq0 = w * 64;
  const size_t xrow = (size_t)Sn * Fn;

  float acc[4][16];
#pragma unroll
  for (int i = 0; i < 4; ++i)
#pragma unroll
    for (int k = 0; k < 16; ++k) acc[i][k] = 0.f;

  // chunk c, batch j: 1 KB contiguous = x[b0+j][sq0+4c .. +4c+3][0..63]
  auto xld = [&](int c, int j) -> float4 {
    const float* p = x + (size_t)(b0 + j) * xrow + (size_t)(sq0 + c * 4) * Fn + lane * 4;
    float4 v = *reinterpret_cast<const float4*>(p);
    v.x = (v.x == v.x) ? v.x : 0.f;    // NaN -> 0 per reference
    v.y = (v.y == v.y) ? v.y : 0.f;
    v.z = (v.z == v.z) ? v.z : 0.f;
    v.w = (v.w == v.w) ? v.w : 0.f;
    return v;
  };
  // plane(p, w, j) = 256 floats; thread writes its float4 at +lane*4
  auto dswr = [&](int p, int j, float4 v) {
    float* pl = stage + ((((p * 4 + w) * 4 + j) << 8) + lane * 4);
    *reinterpret_cast<float4*>(pl) = v;
  };

  float4 xb[4];
#pragma unroll
  for (int j = 0; j < 4; ++j) xb[j] = xld(0, j);
#pragma unroll
  for (int j = 0; j < 4; ++j) dswr(0, j, xb[j]);
#pragma unroll
  for (int j = 0; j < 4; ++j) xb[j] = xld(1, j);

#pragma unroll 2
  for (int c = 0; c < 16; ++c) {
    const int p = c & 1;
    // compute chunk c from stage[p]
#pragma unroll
    for (int s4 = 0; s4 < 4; ++s4) {
      const int s = sq0 + c * 4 + s4;
      float wv[16];
      if (TR) {
        const float4* wp = reinterpret_cast<const float4*>(Wsrc + ((size_t)(s * Fn + lane) << 4));
#pragma unroll
        for (int j = 0; j < 4; ++j) {
          float4 q = wp[j];
          wv[4 * j + 0] = q.x; wv[4 * j + 1] = q.y; wv[4 * j + 2] = q.z; wv[4 * j + 3] = q.w;
        }
      } else {
        const float4* wp = reinterpret_cast<const float4*>(Wsrc + ((size_t)(lane * Sn + s) << 4));
#pragma unroll
        for (int j = 0; j < 4; ++j) {
          float4 q = wp[j];
          wv[4 * j + 0] = q.x; wv[4 * j + 1] = q.y; wv[4 * j + 2] = q.z; wv[4 * j + 3] = q.w;
        }
      }
      float xs[4];
#pragma unroll
      for (int i = 0; i < 4; ++i)
        xs[i] = stage[(((p * 4 + w) * 4 + i) << 8) + s4 * 64 + lane];
#pragma unroll
      for (int i = 0; i < 4; ++i)
#pragma unroll
        for (int k = 0; k < 16; ++k)
          acc[i][k] = fmaf(xs[i], wv[k], acc[i][k]);
    }
    // stage chunk c+1 (regs already loaded), prefetch chunk c+2
    if (c + 1 < 16) {
#pragma unroll
      for (int j = 0; j < 4; ++j) dswr(p ^ 1, j, xb[j]);
    }
    if (c + 2 < 16) {
#pragma unroll
      for (int j = 0; j < 4; ++j) xb[j] = xld(c + 2, j);
    }
  }

  // --- staging region done; reuse it for the cross-wave tree reduce ---
  __syncthreads();
  if (w >= 2) {
#pragma unroll
    for (int i = 0; i < 4; ++i)
#pragma unroll
      for (int k = 0; k < 16; ++k) red[w - 2][i][k][lane] = acc[i][k];
  }
  __syncthreads();
  if (w < 2) {
#pragma unroll
    for (int i = 0; i < 4; ++i)
#pragma unroll
      for (int k = 0; k < 16; ++k) acc[i][k] += red[w][i][k][lane];
  }
  if (w == 1) {
#pragma unroll
    for (int i = 0; i < 4; ++i)
#pragma unroll
      for (int k = 0; k < 16; ++k) red[1][i][k][lane] = acc[i][k];
  }
  __syncthreads();
  if (w == 0) {
#pragma unroll
    for (int i = 0; i < 4; ++i) {
#pragma unroll
      for (int k = 0; k < 16; ++k) acc[i][k] += red[1][i][k][lane];
      float bv = acc[i][0];
      int bk = 0;
#pragma unroll
      for (int k = 1; k < 16; ++k)
        if (acc[i][k] > bv) { bv = acc[i][k]; bk = k; }  // strict >: first max wins
      idxs[i][lane] = bk;
    }
  }
  __syncthreads();

  // gather: 4 b * 64 f = 256 rows of 1 KB; coalesced float4
#pragma unroll 4
  for (int it = 0; it < 64; ++it) {
    int r = (it << 2) | w;
    int bi = r >> 6, f = r & 63;
    int kk = idxs[bi][f];
    float4 v = snip4[(size_t)((f * Kn + kk) << 6) + lane];
    out4[((size_t)(b0 + bi) * Fn + f) * 64 + lane] = v;
  }
}

extern "C" void kernel_launch(void* const* d_in, const int* in_sizes, int n_in,
                              void* d_out, int out_size, void* d_ws, size_t ws_size,
                              hipStream_t stream) {
  const float* x = (const float*)d_in[0];
  const float* W = (const float*)d_in[1];
  const float* snip = (const float*)d_in[2];
  float4* out4 = (float4*)d_out;
  const float4* snip4 = (const float4*)snip;

  const size_t wt_bytes = (size_t)Sn * Fn * Kn * sizeof(float);
  if (ws_size >= wt_bytes) {
    float* Wt = (float*)d_ws;
    transpose_w_kernel<<<(Sn * Fn * Kn) / 256, 256, 0, stream>>>(W, Wt);
    fused_kernel<true><<<Bn / 4, 256, 0, stream>>>(x, Wt, snip4, out4);
  } else {
    fused_kernel<false><<<Bn / 4, 256, 0, stream>>>(x, W, snip4, out4);
  }
}

// Round 5
// 194.320 us; speedup vs baseline: 3.6820x; 3.6820x over previous
//
#include <hip/hip_runtime.h>

// Problem: B=4096, S=256, F=64, K=16, L=256
//   logits[b,k,f] = sum_s x[b,s,f] * W[f,s,k]   (x NaN->0)
//   idx[b,f] = argmax_k logits[b,k,f]           (first max wins)
//   out[b,f,l] = snippet_list[f, idx[b,f], l]
constexpr int Bn = 4096, Sn = 256, Fn = 64, Kn = 16;

// W[f][s][k] -> Wt[s][f][k]  (1 MB, coalesced)
__global__ void transpose_w_kernel(const float* __restrict__ W, float* __restrict__ Wt) {
  int t = blockIdx.x * 256 + threadIdx.x;     // t == (s*64+f)*16+k
  int k = t & 15, f = (t >> 4) & 63, s = t >> 10;
  Wt[t] = W[(f * Sn + s) * Kn + k];
}

// Block = 256 threads (4 waves). Wave w owns batches b0=blk*8+w*2 +{0,1}
// over the FULL s range (no cross-wave reduce). lane = f.
// acc[2][16] = 32 VGPRs; x register-double-buffered 8 s ahead (16
// independent loads in flight); NaN-fix folded into the buffer copy.
template <bool TR>
__global__ __launch_bounds__(256, 2) void fused_kernel(
    const float* __restrict__ x, const float* __restrict__ Wsrc,
    const float4* __restrict__ snip4, float4* __restrict__ out4) {
  __shared__ int idxs[8][64];  // [b in block][f]

  const int tid = threadIdx.x;
  const int lane = tid & 63;           // f
  const int w = tid >> 6;
  const int bbase = blockIdx.x * 8;
  const int b0 = bbase + w * 2;
  const size_t xrow = (size_t)Sn * Fn;

  float acc0[16], acc1[16];
#pragma unroll
  for (int k = 0; k < 16; ++k) { acc0[k] = 0.f; acc1[k] = 0.f; }

  const float* pc0 = x + (size_t)b0 * xrow + lane;  // batch b0,   s=0, f=lane
  const float* pc1 = pc0 + xrow;                    // batch b0+1

  float xc0[8], xc1[8], xn0[8], xn1[8];
  // preload chunk 0 (raw); chunk = 8 s rows = 512 floats
#pragma unroll
  for (int j = 0; j < 8; ++j) { xn0[j] = pc0[j * 64]; xn1[j] = pc1[j * 64]; }

  for (int c = 0; c < 32; ++c) {
    // commit prefetched chunk with NaN->0 fix (the reg-copy IS the fix)
#pragma unroll
    for (int j = 0; j < 8; ++j) {
      float v0 = xn0[j], v1 = xn1[j];
      xc0[j] = (v0 == v0) ? v0 : 0.f;
      xc1[j] = (v1 == v1) ? v1 : 0.f;
    }
    // issue next chunk's 16 independent loads; consumed next iteration
    if (c < 31) {
      pc0 += 512; pc1 += 512;   // 8 s rows * 64 f
#pragma unroll
      for (int j = 0; j < 8; ++j) { xn0[j] = pc0[j * 64]; xn1[j] = pc1[j * 64]; }
    }
    // compute chunk c
#pragma unroll
    for (int s8 = 0; s8 < 8; ++s8) {
      const int s = c * 8 + s8;
      float wv[16];
      if (TR) {
        // Wt[s][f][k]: row s is 1024 floats = 256 float4; lane's 64 B slice
        const float4* wq = reinterpret_cast<const float4*>(Wsrc) + (size_t)s * 256 + lane * 4;
#pragma unroll
        for (int jj = 0; jj < 4; ++jj) {
          float4 q = wq[jj];
          wv[4 * jj + 0] = q.x; wv[4 * jj + 1] = q.y; wv[4 * jj + 2] = q.z; wv[4 * jj + 3] = q.w;
        }
      } else {
        // W[f][s][k]: (lane*256 + s) rows of 16 floats = 4 float4
        const float4* wq = reinterpret_cast<const float4*>(Wsrc) + ((size_t)(lane * Sn + s) << 2);
#pragma unroll
        for (int jj = 0; jj < 4; ++jj) {
          float4 q = wq[jj];
          wv[4 * jj + 0] = q.x; wv[4 * jj + 1] = q.y; wv[4 * jj + 2] = q.z; wv[4 * jj + 3] = q.w;
        }
      }
#pragma unroll
      for (int k = 0; k < 16; ++k) {
        acc0[k] = fmaf(xc0[s8], wv[k], acc0[k]);
        acc1[k] = fmaf(xc1[s8], wv[k], acc1[k]);
      }
    }
  }

  // per-thread argmax (strict >, ascending k: first max wins)
  {
    float bv0 = acc0[0], bv1 = acc1[0];
    int bk0 = 0, bk1 = 0;
#pragma unroll
    for (int k = 1; k < 16; ++k) {
      if (acc0[k] > bv0) { bv0 = acc0[k]; bk0 = k; }
      if (acc1[k] > bv1) { bv1 = acc1[k]; bk1 = k; }
    }
    idxs[w * 2 + 0][lane] = bk0;
    idxs[w * 2 + 1][lane] = bk1;
  }
  __syncthreads();

  // gather: 8 b * 64 f = 512 rows of 1 KB; 4 consecutive rows per round
  // across the 4 waves -> 4 KB contiguous writes, fully coalesced
#pragma unroll 4
  for (int it = 0; it < 128; ++it) {
    int r = (it << 2) | w;
    int bi = r >> 6, f = r & 63;
    int kk = idxs[bi][f];
    float4 v = snip4[(size_t)((f * Kn + kk) << 6) + lane];
    out4[((size_t)(bbase + bi) * Fn + f) * 64 + lane] = v;
  }
}

extern "C" void kernel_launch(void* const* d_in, const int* in_sizes, int n_in,
                              void* d_out, int out_size, void* d_ws, size_t ws_size,
                              hipStream_t stream) {
  const float* x = (const float*)d_in[0];
  const float* W = (const float*)d_in[1];
  const float* snip = (const float*)d_in[2];
  float4* out4 = (float4*)d_out;
  const float4* snip4 = (const float4*)snip;

  const size_t wt_bytes = (size_t)Sn * Fn * Kn * sizeof(float);
  if (ws_size >= wt_bytes) {
    float* Wt = (float*)d_ws;
    transpose_w_kernel<<<(Sn * Fn * Kn) / 256, 256, 0, stream>>>(W, Wt);
    fused_kernel<true><<<Bn / 8, 256, 0, stream>>>(x, Wt, snip4, out4);
  } else {
    fused_kernel<false><<<Bn / 8, 256, 0, stream>>>(x, W, snip4, out4);
  }
}